// Round 1
// baseline (4188.200 us; speedup 1.0000x reference)
//
#include <hip/hip_runtime.h>

// Problem constants (from reference)
#define N_LIC 40000
#define N_EMP 80000
#define N_CON 60000
#define D_LIC 256
#define D_EMP 128
#define D_CON 192
#define HDIM  256
#define E_P   1280000
#define E_Q   640000

// -------------------- workspace layout (floats) --------------------
// [ aggp 40000x128 | aggq 40000x192 | degp 40000 | degq 40000 | Wrs 256x256 | bias 256 ]
#define OFF_AGGP 0
#define OFF_AGGQ (N_LIC * D_EMP)                       // 5,120,000
#define OFF_DEGP (OFF_AGGQ + N_LIC * D_CON)            // 12,800,000
#define OFF_DEGQ (OFF_DEGP + N_LIC)                    // 12,840,000
#define OFF_WRS  (OFF_DEGQ + N_LIC)                    // 12,880,000
#define OFF_BIAS (OFF_WRS + 256 * 256)                 // 12,945,536
#define ZERO_FLOATS OFF_WRS                            // agg + deg need zeroing

// -------------------- prep: Wr_sum = Wr_p + Wr_q, bias = b_p + b_q --------------------
__global__ void prep_kernel(const float* __restrict__ Wrp, const float* __restrict__ Wrq,
                            const float* __restrict__ bp, const float* __restrict__ bq,
                            float* __restrict__ Wrs, float* __restrict__ bias) {
    int tid = blockIdx.x * 256 + threadIdx.x;
    if (tid < 256 * 256) {
        Wrs[tid] = Wrp[tid] + Wrq[tid];
    } else if (tid < 256 * 256 + 256) {
        int j = tid - 256 * 256;
        bias[j] = bp[j] + bq[j];
    }
}

// -------------------- degree accumulation --------------------
__global__ void deg_kernel(const int* __restrict__ dst, float* __restrict__ deg, int E) {
    int tid = blockIdx.x * 256 + threadIdx.x;
    if (tid < E) atomicAdd(&deg[dst[tid]], 1.0f);
}

// -------------------- invert degrees (zero-degree -> 1/1, agg stays 0) --------------------
__global__ void invdeg_kernel(float* __restrict__ degp, float* __restrict__ degq) {
    int tid = blockIdx.x * 256 + threadIdx.x;
    if (tid < N_LIC) {
        degp[tid] = 1.0f / fmaxf(degp[tid], 1.0f);
        degq[tid] = 1.0f / fmaxf(degq[tid], 1.0f);
    }
}

// -------------------- edge-parallel scatter-sum (atomics) --------------------
// D/4 threads per edge; each thread gathers a float4 from x_src and atomicAdds into agg[dst]
template<int D>
__global__ void scatter_kernel(const float* __restrict__ x, const int* __restrict__ src,
                               const int* __restrict__ dst, float* __restrict__ agg, int E) {
    constexpr int C = D / 4;
    int tid = blockIdx.x * 256 + threadIdx.x;
    if (tid >= E * C) return;
    int e = tid / C;
    int c = tid - e * C;
    int s = src[e];
    int d = dst[e];
    float4 v = *(const float4*)(x + (size_t)s * D + c * 4);
    float* o = agg + (size_t)d * D + c * 4;
    atomicAdd(o + 0, v.x);
    atomicAdd(o + 1, v.y);
    atomicAdd(o + 2, v.z);
    atomicAdd(o + 3, v.w);
}

// -------------------- fused GEMM + bias + relu --------------------
// C[40000,256] = relu(0.5*( [aggp*invdp | aggq*invdq | xlic] @ [Wlp; Wlq; Wrs] + bias ))
// BM=64, BN=64, BK=16, 256 threads, 4x4 microtile.
__global__ __launch_bounds__(256) void gemm_kernel(
    const float* __restrict__ aggp, const float* __restrict__ aggq,
    const float* __restrict__ xlic,
    const float* __restrict__ invdp, const float* __restrict__ invdq,
    const float* __restrict__ Wlp, const float* __restrict__ Wlq,
    const float* __restrict__ Wrs, const float* __restrict__ bias,
    float* __restrict__ out)
{
    __shared__ float As[16][68];  // [k][m], padded
    __shared__ float Bs[16][64];  // [k][n]

    const int t  = threadIdx.x;
    const int m0 = blockIdx.x * 64;
    const int n0 = blockIdx.y * 64;
    const int tx = t & 15;        // N dir (16 x 4 cols)
    const int ty = t >> 4;        // M dir (16 x 4 rows)
    const int lr = t >> 2;        // A-load row 0..63
    const int lk = (t & 3) * 4;   // A-load k-quad
    const int bk = t >> 4;        // B-load k row 0..15
    const int bn = (t & 15) * 4;  // B-load col quad

    float acc[4][4] = {};

    for (int k0 = 0; k0 < 576; k0 += 16) {
        const float* Asrc; const float* Bsrc; const float* scale; int ldA; int ko;
        if (k0 < 128)       { Asrc = aggp; scale = invdp;   ldA = 128; ko = k0;       Bsrc = Wlp; }
        else if (k0 < 320)  { Asrc = aggq; scale = invdq;   ldA = 192; ko = k0 - 128; Bsrc = Wlq; }
        else                { Asrc = xlic; scale = nullptr; ldA = 256; ko = k0 - 320; Bsrc = Wrs; }

        float4 av = *(const float4*)(Asrc + (size_t)(m0 + lr) * ldA + ko + lk);
        float sc = scale ? scale[m0 + lr] : 1.0f;
        As[lk + 0][lr] = av.x * sc;
        As[lk + 1][lr] = av.y * sc;
        As[lk + 2][lr] = av.z * sc;
        As[lk + 3][lr] = av.w * sc;

        float4 bv = *(const float4*)(Bsrc + (size_t)(ko + bk) * 256 + n0 + bn);
        *(float4*)&Bs[bk][bn] = bv;

        __syncthreads();

        #pragma unroll
        for (int kk = 0; kk < 16; kk++) {
            float a0 = As[kk][ty * 4 + 0];
            float a1 = As[kk][ty * 4 + 1];
            float a2 = As[kk][ty * 4 + 2];
            float a3 = As[kk][ty * 4 + 3];
            float b0 = Bs[kk][tx * 4 + 0];
            float b1 = Bs[kk][tx * 4 + 1];
            float b2 = Bs[kk][tx * 4 + 2];
            float b3 = Bs[kk][tx * 4 + 3];
            acc[0][0] += a0 * b0; acc[0][1] += a0 * b1; acc[0][2] += a0 * b2; acc[0][3] += a0 * b3;
            acc[1][0] += a1 * b0; acc[1][1] += a1 * b1; acc[1][2] += a1 * b2; acc[1][3] += a1 * b3;
            acc[2][0] += a2 * b0; acc[2][1] += a2 * b1; acc[2][2] += a2 * b2; acc[2][3] += a2 * b3;
            acc[3][0] += a3 * b0; acc[3][1] += a3 * b1; acc[3][2] += a3 * b2; acc[3][3] += a3 * b3;
        }

        __syncthreads();
    }

    #pragma unroll
    for (int i = 0; i < 4; i++) {
        int row = m0 + ty * 4 + i;
        #pragma unroll
        for (int j = 0; j < 4; j++) {
            int col = n0 + tx * 4 + j;
            float v = 0.5f * (acc[i][j] + bias[col]);
            out[(size_t)row * 256 + col] = fmaxf(v, 0.0f);
        }
    }
}

// -------------------- launch --------------------
extern "C" void kernel_launch(void* const* d_in, const int* in_sizes, int n_in,
                              void* d_out, int out_size, void* d_ws, size_t ws_size,
                              hipStream_t stream) {
    const float* x_lic = (const float*)d_in[0];
    const float* x_emp = (const float*)d_in[1];
    const float* x_con = (const float*)d_in[2];
    const float* Wl_p  = (const float*)d_in[3];
    const float* Wr_p  = (const float*)d_in[4];
    const float* b_p   = (const float*)d_in[5];
    const float* Wl_q  = (const float*)d_in[6];
    const float* Wr_q  = (const float*)d_in[7];
    const float* b_q   = (const float*)d_in[8];
    const int* ei_p_src = (const int*)d_in[9];
    const int* ei_p_dst = (const int*)d_in[10];
    const int* ei_q_src = (const int*)d_in[11];
    const int* ei_q_dst = (const int*)d_in[12];

    float* ws   = (float*)d_ws;
    float* aggp = ws + OFF_AGGP;
    float* aggq = ws + OFF_AGGQ;
    float* degp = ws + OFF_DEGP;
    float* degq = ws + OFF_DEGQ;
    float* Wrs  = ws + OFF_WRS;
    float* bias = ws + OFF_BIAS;
    float* out  = (float*)d_out;

    // zero the accumulators (ws is poisoned to 0xAA before every call)
    hipMemsetAsync(ws, 0, (size_t)ZERO_FLOATS * sizeof(float), stream);

    // prep weights
    prep_kernel<<<(256 * 256 + 256 + 255) / 256, 256, 0, stream>>>(Wr_p, Wr_q, b_p, b_q, Wrs, bias);

    // degrees
    deg_kernel<<<(E_P + 255) / 256, 256, 0, stream>>>(ei_p_dst, degp, E_P);
    deg_kernel<<<(E_Q + 255) / 256, 256, 0, stream>>>(ei_q_dst, degq, E_Q);
    invdeg_kernel<<<(N_LIC + 255) / 256, 256, 0, stream>>>(degp, degq);

    // scatter-sum
    {
        int total = E_P * (D_EMP / 4);
        scatter_kernel<D_EMP><<<(total + 255) / 256, 256, 0, stream>>>(x_emp, ei_p_src, ei_p_dst, aggp, E_P);
    }
    {
        int total = E_Q * (D_CON / 4);
        scatter_kernel<D_CON><<<(total + 255) / 256, 256, 0, stream>>>(x_con, ei_q_src, ei_q_dst, aggq, E_Q);
    }

    // fused GEMM + bias + relu
    dim3 grid(N_LIC / 64, HDIM / 64);
    gemm_kernel<<<grid, 256, 0, stream>>>(aggp, aggq, x_lic, degp, degq,
                                          Wl_p, Wl_q, Wrs, bias, out);
}

// Round 2
// 765.273 us; speedup vs baseline: 5.4728x; 5.4728x over previous
//
#include <hip/hip_runtime.h>

// Problem constants
#define N_LIC 40000
#define N_EMP 80000
#define N_CON 60000
#define D_EMP 128
#define D_CON 192
#define HDIM  256
#define E_P   1280000
#define E_Q   640000

// -------------------- workspace layout (4-byte elements) --------------------
#define OFF_AGGP   0                                   // 40000*128 f
#define OFF_AGGQ   (OFF_AGGP + N_LIC * D_EMP)          // 40000*192 f
#define OFF_CNT    (OFF_AGGQ + N_LIC * D_CON)          // 80000 i  (P then Q)
#define OFF_OFFP   (OFF_CNT + 2 * N_LIC)               // 40001 i
#define OFF_OFFQ   (OFF_OFFP + N_LIC + 1)              // 40001 i
#define OFF_CURP   (OFF_OFFQ + N_LIC + 1)              // 40000 i
#define OFF_CURQ   (OFF_CURP + N_LIC)                  // 40000 i
#define OFF_SRTP   (OFF_CURQ + N_LIC)                  // 1280000 i
#define OFF_SRTQ   (OFF_SRTP + E_P)                    // 640000 i
#define OFF_WRS    (OFF_SRTQ + E_Q)                    // 65536 f
#define OFF_BIAS   (OFF_WRS + 256 * 256)               // 256 f

// -------------------- prep: Wr_sum = Wr_p + Wr_q, bias = b_p + b_q --------------------
__global__ void prep_kernel(const float* __restrict__ Wrp, const float* __restrict__ Wrq,
                            const float* __restrict__ bp, const float* __restrict__ bq,
                            float* __restrict__ Wrs, float* __restrict__ bias) {
    int tid = blockIdx.x * 256 + threadIdx.x;
    if (tid < 256 * 256) {
        Wrs[tid] = Wrp[tid] + Wrq[tid];
    } else if (tid < 256 * 256 + 256) {
        int j = tid - 256 * 256;
        bias[j] = bp[j] + bq[j];
    }
}

// -------------------- histogram of dst --------------------
__global__ void count_kernel(const int* __restrict__ dst, int* __restrict__ cnt, int E) {
    int tid = blockIdx.x * 256 + threadIdx.x;
    if (tid < E) atomicAdd(&cnt[dst[tid]], 1);
}

// -------------------- single-block exclusive scan (one block per relation) -------------
__global__ __launch_bounds__(1024) void scan_kernel(const int* __restrict__ cnt_all,
                                                    int* __restrict__ offp,
                                                    int* __restrict__ offq) {
    const int rel = blockIdx.x;
    const int* cnt = cnt_all + rel * N_LIC;
    int* offs = rel == 0 ? offp : offq;
    const int CH = 40;  // 1024*40 >= 40000
    int t = threadIdx.x;
    int base = t * CH;
    int s = 0;
    #pragma unroll 4
    for (int i = 0; i < CH; i++) {
        int idx = base + i;
        if (idx < N_LIC) s += cnt[idx];
    }
    __shared__ int part[1024];
    part[t] = s;
    __syncthreads();
    for (int off = 1; off < 1024; off <<= 1) {
        int v = (t >= off) ? part[t - off] : 0;
        __syncthreads();
        part[t] += v;
        __syncthreads();
    }
    int run = (t > 0) ? part[t - 1] : 0;  // exclusive base
    for (int i = 0; i < CH; i++) {
        int idx = base + i;
        if (idx < N_LIC) {
            offs[idx] = run;
            run += cnt[idx];
        }
    }
    if (t == 0) offs[N_LIC] = part[1023];
}

// -------------------- cursor init = offsets --------------------
__global__ void cursor_kernel(const int* __restrict__ offp, const int* __restrict__ offq,
                              int* __restrict__ curp, int* __restrict__ curq) {
    int tid = blockIdx.x * 256 + threadIdx.x;
    if (tid < N_LIC) curp[tid] = offp[tid];
    else if (tid < 2 * N_LIC) curq[tid - N_LIC] = offq[tid - N_LIC];
}

// -------------------- bucket-fill: sorted src per dst --------------------
__global__ void fill_kernel(const int* __restrict__ src, const int* __restrict__ dst,
                            int* __restrict__ cur, int* __restrict__ sorted, int E) {
    int tid = blockIdx.x * 256 + threadIdx.x;
    if (tid < E) {
        int pos = atomicAdd(&cur[dst[tid]], 1);
        sorted[pos] = src[tid];
    }
}

// -------------------- aggregate P: 32 lanes per node, D=128 --------------------
__global__ __launch_bounds__(256) void aggP_kernel(const float* __restrict__ x,
                                                   const int* __restrict__ offs,
                                                   const int* __restrict__ sorted,
                                                   float* __restrict__ agg) {
    int g = blockIdx.x * 8 + (threadIdx.x >> 5);   // node
    int c = threadIdx.x & 31;                      // float4 column
    int beg = offs[g], end = offs[g + 1];
    float4 acc = {0.f, 0.f, 0.f, 0.f};
    for (int eb = beg; eb < end; eb += 32) {
        int n = end - eb; if (n > 32) n = 32;
        int my = (c < n) ? sorted[eb + c] : 0;
        for (int j = 0; j < n; j++) {
            int s = __shfl(my, j, 32);
            float4 v = *(const float4*)(x + (size_t)s * D_EMP + c * 4);
            acc.x += v.x; acc.y += v.y; acc.z += v.z; acc.w += v.w;
        }
    }
    float inv = 1.0f / fmaxf((float)(end - beg), 1.0f);
    float4 o = {acc.x * inv, acc.y * inv, acc.z * inv, acc.w * inv};
    *(float4*)(agg + (size_t)g * D_EMP + c * 4) = o;
}

// -------------------- aggregate Q: 16 lanes per node, D=192 (3 float4/lane) -----------
__global__ __launch_bounds__(256) void aggQ_kernel(const float* __restrict__ x,
                                                   const int* __restrict__ offs,
                                                   const int* __restrict__ sorted,
                                                   float* __restrict__ agg) {
    int g = blockIdx.x * 16 + (threadIdx.x >> 4);  // node
    int c = threadIdx.x & 15;                      // lane in group; owns floats [c*12, c*12+12)
    int beg = offs[g], end = offs[g + 1];
    float4 a0 = {0,0,0,0}, a1 = {0,0,0,0}, a2 = {0,0,0,0};
    for (int eb = beg; eb < end; eb += 16) {
        int n = end - eb; if (n > 16) n = 16;
        int my = (c < n) ? sorted[eb + c] : 0;
        for (int j = 0; j < n; j++) {
            int s = __shfl(my, j, 16);
            const float* row = x + (size_t)s * D_CON + c * 12;
            float4 v0 = *(const float4*)(row + 0);
            float4 v1 = *(const float4*)(row + 4);
            float4 v2 = *(const float4*)(row + 8);
            a0.x += v0.x; a0.y += v0.y; a0.z += v0.z; a0.w += v0.w;
            a1.x += v1.x; a1.y += v1.y; a1.z += v1.z; a1.w += v1.w;
            a2.x += v2.x; a2.y += v2.y; a2.z += v2.z; a2.w += v2.w;
        }
    }
    float inv = 1.0f / fmaxf((float)(end - beg), 1.0f);
    float* o = agg + (size_t)g * D_CON + c * 12;
    float4 w0 = {a0.x*inv, a0.y*inv, a0.z*inv, a0.w*inv};
    float4 w1 = {a1.x*inv, a1.y*inv, a1.z*inv, a1.w*inv};
    float4 w2 = {a2.x*inv, a2.y*inv, a2.z*inv, a2.w*inv};
    *(float4*)(o + 0) = w0;
    *(float4*)(o + 4) = w1;
    *(float4*)(o + 8) = w2;
}

// -------------------- fused GEMM + bias + relu --------------------
// C[40000,256] = relu(0.5*( [aggp | aggq | xlic] @ [Wlp; Wlq; Wrs] + bias ))
__global__ __launch_bounds__(256) void gemm_kernel(
    const float* __restrict__ aggp, const float* __restrict__ aggq,
    const float* __restrict__ xlic,
    const float* __restrict__ Wlp, const float* __restrict__ Wlq,
    const float* __restrict__ Wrs, const float* __restrict__ bias,
    float* __restrict__ out)
{
    __shared__ float As[16][68];  // [k][m], padded
    __shared__ float Bs[16][64];  // [k][n]

    const int t  = threadIdx.x;
    const int m0 = blockIdx.x * 64;
    const int n0 = blockIdx.y * 64;
    const int tx = t & 15;
    const int ty = t >> 4;
    const int lr = t >> 2;
    const int lk = (t & 3) * 4;
    const int bk = t >> 4;
    const int bn = (t & 15) * 4;

    float acc[4][4] = {};

    for (int k0 = 0; k0 < 576; k0 += 16) {
        const float* Asrc; const float* Bsrc; int ldA; int ko;
        if (k0 < 128)       { Asrc = aggp; ldA = 128; ko = k0;       Bsrc = Wlp; }
        else if (k0 < 320)  { Asrc = aggq; ldA = 192; ko = k0 - 128; Bsrc = Wlq; }
        else                { Asrc = xlic; ldA = 256; ko = k0 - 320; Bsrc = Wrs; }

        float4 av = *(const float4*)(Asrc + (size_t)(m0 + lr) * ldA + ko + lk);
        As[lk + 0][lr] = av.x;
        As[lk + 1][lr] = av.y;
        As[lk + 2][lr] = av.z;
        As[lk + 3][lr] = av.w;

        float4 bv = *(const float4*)(Bsrc + (size_t)(ko + bk) * 256 + n0 + bn);
        *(float4*)&Bs[bk][bn] = bv;

        __syncthreads();

        #pragma unroll
        for (int kk = 0; kk < 16; kk++) {
            float a0 = As[kk][ty * 4 + 0];
            float a1 = As[kk][ty * 4 + 1];
            float a2 = As[kk][ty * 4 + 2];
            float a3 = As[kk][ty * 4 + 3];
            float b0 = Bs[kk][tx * 4 + 0];
            float b1 = Bs[kk][tx * 4 + 1];
            float b2 = Bs[kk][tx * 4 + 2];
            float b3 = Bs[kk][tx * 4 + 3];
            acc[0][0] += a0 * b0; acc[0][1] += a0 * b1; acc[0][2] += a0 * b2; acc[0][3] += a0 * b3;
            acc[1][0] += a1 * b0; acc[1][1] += a1 * b1; acc[1][2] += a1 * b2; acc[1][3] += a1 * b3;
            acc[2][0] += a2 * b0; acc[2][1] += a2 * b1; acc[2][2] += a2 * b2; acc[2][3] += a2 * b3;
            acc[3][0] += a3 * b0; acc[3][1] += a3 * b1; acc[3][2] += a3 * b2; acc[3][3] += a3 * b3;
        }

        __syncthreads();
    }

    #pragma unroll
    for (int i = 0; i < 4; i++) {
        int row = m0 + ty * 4 + i;
        #pragma unroll
        for (int j = 0; j < 4; j++) {
            int col = n0 + tx * 4 + j;
            float v = 0.5f * (acc[i][j] + bias[col]);
            out[(size_t)row * 256 + col] = fmaxf(v, 0.0f);
        }
    }
}

// -------------------- launch --------------------
extern "C" void kernel_launch(void* const* d_in, const int* in_sizes, int n_in,
                              void* d_out, int out_size, void* d_ws, size_t ws_size,
                              hipStream_t stream) {
    const float* x_lic = (const float*)d_in[0];
    const float* x_emp = (const float*)d_in[1];
    const float* x_con = (const float*)d_in[2];
    const float* Wl_p  = (const float*)d_in[3];
    const float* Wr_p  = (const float*)d_in[4];
    const float* b_p   = (const float*)d_in[5];
    const float* Wl_q  = (const float*)d_in[6];
    const float* Wr_q  = (const float*)d_in[7];
    const float* b_q   = (const float*)d_in[8];
    const int* ei_p_src = (const int*)d_in[9];
    const int* ei_p_dst = (const int*)d_in[10];
    const int* ei_q_src = (const int*)d_in[11];
    const int* ei_q_dst = (const int*)d_in[12];

    float* ws   = (float*)d_ws;
    float* aggp = ws + OFF_AGGP;
    float* aggq = ws + OFF_AGGQ;
    int*   cnt  = (int*)(ws + OFF_CNT);
    int*   offp = (int*)(ws + OFF_OFFP);
    int*   offq = (int*)(ws + OFF_OFFQ);
    int*   curp = (int*)(ws + OFF_CURP);
    int*   curq = (int*)(ws + OFF_CURQ);
    int*   srtp = (int*)(ws + OFF_SRTP);
    int*   srtq = (int*)(ws + OFF_SRTQ);
    float* Wrs  = ws + OFF_WRS;
    float* bias = ws + OFF_BIAS;
    float* out  = (float*)d_out;

    // zero only the histograms (ws is re-poisoned before every call)
    hipMemsetAsync(cnt, 0, 2 * N_LIC * sizeof(int), stream);

    prep_kernel<<<(256 * 256 + 256 + 255) / 256, 256, 0, stream>>>(Wr_p, Wr_q, b_p, b_q, Wrs, bias);

    count_kernel<<<(E_P + 255) / 256, 256, 0, stream>>>(ei_p_dst, cnt, E_P);
    count_kernel<<<(E_Q + 255) / 256, 256, 0, stream>>>(ei_q_dst, cnt + N_LIC, E_Q);

    scan_kernel<<<2, 1024, 0, stream>>>(cnt, offp, offq);

    cursor_kernel<<<(2 * N_LIC + 255) / 256, 256, 0, stream>>>(offp, offq, curp, curq);

    fill_kernel<<<(E_P + 255) / 256, 256, 0, stream>>>(ei_p_src, ei_p_dst, curp, srtp, E_P);
    fill_kernel<<<(E_Q + 255) / 256, 256, 0, stream>>>(ei_q_src, ei_q_dst, curq, srtq, E_Q);

    aggP_kernel<<<N_LIC / 8, 256, 0, stream>>>(x_emp, offp, srtp, aggp);
    aggQ_kernel<<<N_LIC / 16, 256, 0, stream>>>(x_con, offq, srtq, aggq);

    dim3 grid(N_LIC / 64, HDIM / 64);
    gemm_kernel<<<grid, 256, 0, stream>>>(aggp, aggq, x_lic, Wl_p, Wl_q, Wrs, bias, out);
}

// Round 3
// 686.531 us; speedup vs baseline: 6.1005x; 1.1147x over previous
//
#include <hip/hip_runtime.h>

// Problem constants
#define N_LIC 40000
#define N_EMP 80000
#define N_CON 60000
#define D_EMP 128
#define D_CON 192
#define HDIM  256
#define E_P   1280000
#define E_Q   640000

// -------------------- workspace layout (4-byte units) --------------------
#define OFF_AGGP   0                                   // 40000x128 bf16 -> 2,560,000 dw
#define OFF_AGGQ   (OFF_AGGP + 2560000)                // 40000x192 bf16 -> 3,840,000 dw
#define OFF_XL     (OFF_AGGQ + 3840000)                // 40000x256 bf16 -> 5,120,000 dw
#define OFF_BPK    (OFF_XL + 5120000)                  // 256x576 bf16 -> 73,728 dw
#define OFF_BIAS   (OFF_BPK + 73728)                   // 256 f
#define OFF_CNT    (OFF_BIAS + 256)                    // 80000 i (P then Q)
#define OFF_OFFP   (OFF_CNT + 2 * N_LIC)               // 40001 i
#define OFF_OFFQ   (OFF_OFFP + N_LIC + 1)              // 40001 i
#define OFF_CURP   (OFF_OFFQ + N_LIC + 1)              // 40000 i
#define OFF_CURQ   (OFF_CURP + N_LIC)                  // 40000 i
#define OFF_SRTP   (OFF_CURQ + N_LIC)                  // 1,280,000 i
#define OFF_SRTQ   (OFF_SRTP + E_P)                    // 640,000 i
// total ~13.75M dw = 55 MB

typedef short bf16x8 __attribute__((ext_vector_type(8)));
typedef float f32x4 __attribute__((ext_vector_type(4)));

__device__ __forceinline__ ushort f2bf(float f) {
    union { float f; uint u; } v; v.f = f;
    return (ushort)((v.u + 0x7fffu + ((v.u >> 16) & 1u)) >> 16);
}

// -------------------- prep: pack B = [Wl_p; Wl_q; Wr_p+Wr_q] transposed to [n][k] bf16 ----
__global__ void prep_kernel(const float* __restrict__ Wlp, const float* __restrict__ Wlq,
                            const float* __restrict__ Wrp, const float* __restrict__ Wrq,
                            const float* __restrict__ bp, const float* __restrict__ bq,
                            ushort* __restrict__ Bpk, float* __restrict__ bias) {
    int tid = blockIdx.x * 256 + threadIdx.x;
    if (tid < 256 * 576) {
        int n = tid / 576, k = tid - n * 576;
        float v;
        if (k < 128)      v = Wlp[k * 256 + n];
        else if (k < 320) v = Wlq[(k - 128) * 256 + n];
        else              v = Wrp[(k - 320) * 256 + n] + Wrq[(k - 320) * 256 + n];
        Bpk[tid] = f2bf(v);
    } else if (tid < 256 * 576 + 256) {
        int j = tid - 256 * 576;
        bias[j] = bp[j] + bq[j];
    }
}

// -------------------- convert x_lic to bf16 (1 float4 per thread) --------------------
__global__ void convert_kernel(const float* __restrict__ x, ushort* __restrict__ y) {
    int tid = blockIdx.x * 256 + threadIdx.x;
    float4 v = ((const float4*)x)[tid];
    uint2 o;
    o.x = (uint)f2bf(v.x) | ((uint)f2bf(v.y) << 16);
    o.y = (uint)f2bf(v.z) | ((uint)f2bf(v.w) << 16);
    ((uint2*)y)[tid] = o;
}

// -------------------- fused histogram of both dst arrays --------------------
__global__ void count_kernel(const int* __restrict__ dp, const int* __restrict__ dq,
                             int* __restrict__ cnt) {
    int tid = blockIdx.x * 256 + threadIdx.x;
    if (tid < E_P) atomicAdd(&cnt[dp[tid]], 1);
    else if (tid < E_P + E_Q) atomicAdd(&cnt[N_LIC + dq[tid - E_P]], 1);
}

// -------------------- single-block exclusive scan + cursor init (one block/relation) ----
__global__ __launch_bounds__(1024) void scan_kernel(const int* __restrict__ cnt_all,
                                                    int* __restrict__ offp, int* __restrict__ offq,
                                                    int* __restrict__ curp, int* __restrict__ curq) {
    const int rel = blockIdx.x;
    const int* cnt = cnt_all + rel * N_LIC;
    int* offs = rel == 0 ? offp : offq;
    int* cur  = rel == 0 ? curp : curq;
    const int CH = 40;
    int t = threadIdx.x;
    int base = t * CH;
    int s = 0;
    #pragma unroll 4
    for (int i = 0; i < CH; i++) {
        int idx = base + i;
        if (idx < N_LIC) s += cnt[idx];
    }
    __shared__ int part[1024];
    part[t] = s;
    __syncthreads();
    for (int off = 1; off < 1024; off <<= 1) {
        int v = (t >= off) ? part[t - off] : 0;
        __syncthreads();
        part[t] += v;
        __syncthreads();
    }
    int run = (t > 0) ? part[t - 1] : 0;
    for (int i = 0; i < CH; i++) {
        int idx = base + i;
        if (idx < N_LIC) {
            offs[idx] = run;
            cur[idx] = run;
            run += cnt[idx];
        }
    }
    if (t == 0) offs[N_LIC] = part[1023];
}

// -------------------- fused bucket-fill --------------------
__global__ void fill_kernel(const int* __restrict__ sp, const int* __restrict__ dp,
                            const int* __restrict__ sq, const int* __restrict__ dq,
                            int* __restrict__ curp, int* __restrict__ curq,
                            int* __restrict__ srtp, int* __restrict__ srtq) {
    int tid = blockIdx.x * 256 + threadIdx.x;
    if (tid < E_P) {
        int pos = atomicAdd(&curp[dp[tid]], 1);
        srtp[pos] = sp[tid];
    } else if (tid < E_P + E_Q) {
        int e = tid - E_P;
        int pos = atomicAdd(&curq[dq[e]], 1);
        srtq[pos] = sq[e];
    }
}

// -------------------- aggregate P: 32 lanes/node, D=128, fp32 in -> bf16 out ------------
__global__ __launch_bounds__(256) void aggP_kernel(const float* __restrict__ x,
                                                   const int* __restrict__ offs,
                                                   const int* __restrict__ sorted,
                                                   ushort* __restrict__ agg) {
    int g = blockIdx.x * 8 + (threadIdx.x >> 5);
    int c = threadIdx.x & 31;
    int beg = offs[g], end = offs[g + 1];
    float4 acc = {0.f, 0.f, 0.f, 0.f};
    for (int eb = beg; eb < end; eb += 32) {
        int n = end - eb; if (n > 32) n = 32;
        int my = (c < n) ? sorted[eb + c] : 0;
        for (int j = 0; j < n; j++) {
            int s = __shfl(my, j, 32);
            float4 v = *(const float4*)(x + (size_t)s * D_EMP + c * 4);
            acc.x += v.x; acc.y += v.y; acc.z += v.z; acc.w += v.w;
        }
    }
    float inv = 1.0f / fmaxf((float)(end - beg), 1.0f);
    uint2 o;
    o.x = (uint)f2bf(acc.x * inv) | ((uint)f2bf(acc.y * inv) << 16);
    o.y = (uint)f2bf(acc.z * inv) | ((uint)f2bf(acc.w * inv) << 16);
    *(uint2*)(agg + (size_t)g * D_EMP + c * 4) = o;
}

// -------------------- aggregate Q: 16 lanes/node, D=192, fp32 in -> bf16 out ------------
__global__ __launch_bounds__(256) void aggQ_kernel(const float* __restrict__ x,
                                                   const int* __restrict__ offs,
                                                   const int* __restrict__ sorted,
                                                   ushort* __restrict__ agg) {
    int g = blockIdx.x * 16 + (threadIdx.x >> 4);
    int c = threadIdx.x & 15;
    int beg = offs[g], end = offs[g + 1];
    float4 a0 = {0,0,0,0}, a1 = {0,0,0,0}, a2 = {0,0,0,0};
    for (int eb = beg; eb < end; eb += 16) {
        int n = end - eb; if (n > 16) n = 16;
        int my = (c < n) ? sorted[eb + c] : 0;
        for (int j = 0; j < n; j++) {
            int s = __shfl(my, j, 16);
            const float* row = x + (size_t)s * D_CON + c * 12;
            float4 v0 = *(const float4*)(row + 0);
            float4 v1 = *(const float4*)(row + 4);
            float4 v2 = *(const float4*)(row + 8);
            a0.x += v0.x; a0.y += v0.y; a0.z += v0.z; a0.w += v0.w;
            a1.x += v1.x; a1.y += v1.y; a1.z += v1.z; a1.w += v1.w;
            a2.x += v2.x; a2.y += v2.y; a2.z += v2.z; a2.w += v2.w;
        }
    }
    float inv = 1.0f / fmaxf((float)(end - beg), 1.0f);
    ushort* o = agg + (size_t)g * D_CON + c * 12;
    uint2 w0, w1, w2;
    w0.x = (uint)f2bf(a0.x*inv) | ((uint)f2bf(a0.y*inv) << 16);
    w0.y = (uint)f2bf(a0.z*inv) | ((uint)f2bf(a0.w*inv) << 16);
    w1.x = (uint)f2bf(a1.x*inv) | ((uint)f2bf(a1.y*inv) << 16);
    w1.y = (uint)f2bf(a1.z*inv) | ((uint)f2bf(a1.w*inv) << 16);
    w2.x = (uint)f2bf(a2.x*inv) | ((uint)f2bf(a2.y*inv) << 16);
    w2.y = (uint)f2bf(a2.z*inv) | ((uint)f2bf(a2.w*inv) << 16);
    *(uint2*)(o + 0) = w0;
    *(uint2*)(o + 4) = w1;
    *(uint2*)(o + 8) = w2;
}

// -------------------- MFMA bf16 GEMM + bias + relu --------------------
// C[40000,256] = relu(0.5*([aggp|aggq|xl] @ B + bias)); B prepacked [n=256][k=576] bf16.
// BM=64, BN=256 (full), BK=32, 4 waves, each wave 64 rows x 64 cols = 4x4 mfma tiles.
__global__ __launch_bounds__(256) void gemm_kernel(
    const ushort* __restrict__ aggp, const ushort* __restrict__ aggq,
    const ushort* __restrict__ xl, const ushort* __restrict__ Bpk,
    const float* __restrict__ bias, float* __restrict__ out)
{
    __shared__ __align__(16) ushort As[64 * 40];   // [m][k], k padded 32->40
    __shared__ __align__(16) ushort Bs[256 * 40];  // [n][k]

    const int t = threadIdx.x;
    const int m0 = blockIdx.x * 64;
    const int lane = t & 63;
    const int wave = t >> 6;
    const int arow = t >> 2;   // 0..63
    const int achk = t & 3;    // 0..3
    const int l15 = lane & 15;
    const int lh  = lane >> 4; // 0..3

    f32x4 acc[4][4];
    #pragma unroll
    for (int i = 0; i < 4; i++)
        #pragma unroll
        for (int j = 0; j < 4; j++)
            acc[i][j] = (f32x4){0.f, 0.f, 0.f, 0.f};

    for (int k0 = 0; k0 < 576; k0 += 32) {
        const ushort* Asrc; int ldA; int ko;
        if (k0 < 128)      { Asrc = aggp; ldA = 128; ko = k0; }
        else if (k0 < 320) { Asrc = aggq; ldA = 192; ko = k0 - 128; }
        else               { Asrc = xl;   ldA = 256; ko = k0 - 320; }

        // stage A tile: 64 rows x 32 k (16B per thread)
        {
            const uint4 v = *(const uint4*)(Asrc + (size_t)(m0 + arow) * ldA + ko + achk * 8);
            *(uint4*)(As + arow * 40 + achk * 8) = v;
        }
        // stage B tile: 256 cols x 32 k (4 x 16B per thread)
        #pragma unroll
        for (int i = 0; i < 4; i++) {
            int col = arow + i * 64;
            const uint4 v = *(const uint4*)(Bpk + (size_t)col * 576 + k0 + achk * 8);
            *(uint4*)(Bs + col * 40 + achk * 8) = v;
        }
        __syncthreads();

        bf16x8 af[4], bfr[4];
        #pragma unroll
        for (int mt = 0; mt < 4; mt++)
            af[mt] = *(const bf16x8*)(As + (mt * 16 + l15) * 40 + lh * 8);
        #pragma unroll
        for (int nt = 0; nt < 4; nt++)
            bfr[nt] = *(const bf16x8*)(Bs + (wave * 64 + nt * 16 + l15) * 40 + lh * 8);

        #pragma unroll
        for (int mt = 0; mt < 4; mt++)
            #pragma unroll
            for (int nt = 0; nt < 4; nt++)
                acc[mt][nt] = __builtin_amdgcn_mfma_f32_16x16x32_bf16(af[mt], bfr[nt], acc[mt][nt], 0, 0, 0);

        __syncthreads();
    }

    // epilogue: C/D layout col=lane&15, row=(lane>>4)*4+reg
    #pragma unroll
    for (int nt = 0; nt < 4; nt++) {
        int n = wave * 64 + nt * 16 + l15;
        float bv = bias[n];
        #pragma unroll
        for (int mt = 0; mt < 4; mt++) {
            #pragma unroll
            for (int r = 0; r < 4; r++) {
                int m = m0 + mt * 16 + lh * 4 + r;
                float v = 0.5f * (acc[mt][nt][r] + bv);
                out[(size_t)m * 256 + n] = fmaxf(v, 0.f);
            }
        }
    }
}

// -------------------- launch --------------------
extern "C" void kernel_launch(void* const* d_in, const int* in_sizes, int n_in,
                              void* d_out, int out_size, void* d_ws, size_t ws_size,
                              hipStream_t stream) {
    const float* x_lic = (const float*)d_in[0];
    const float* x_emp = (const float*)d_in[1];
    const float* x_con = (const float*)d_in[2];
    const float* Wl_p  = (const float*)d_in[3];
    const float* Wr_p  = (const float*)d_in[4];
    const float* b_p   = (const float*)d_in[5];
    const float* Wl_q  = (const float*)d_in[6];
    const float* Wr_q  = (const float*)d_in[7];
    const float* b_q   = (const float*)d_in[8];
    const int* ei_p_src = (const int*)d_in[9];
    const int* ei_p_dst = (const int*)d_in[10];
    const int* ei_q_src = (const int*)d_in[11];
    const int* ei_q_dst = (const int*)d_in[12];

    float* ws = (float*)d_ws;
    ushort* aggp = (ushort*)(ws + OFF_AGGP);
    ushort* aggq = (ushort*)(ws + OFF_AGGQ);
    ushort* xl   = (ushort*)(ws + OFF_XL);
    ushort* Bpk  = (ushort*)(ws + OFF_BPK);
    float* bias  = ws + OFF_BIAS;
    int* cnt  = (int*)(ws + OFF_CNT);
    int* offp = (int*)(ws + OFF_OFFP);
    int* offq = (int*)(ws + OFF_OFFQ);
    int* curp = (int*)(ws + OFF_CURP);
    int* curq = (int*)(ws + OFF_CURQ);
    int* srtp = (int*)(ws + OFF_SRTP);
    int* srtq = (int*)(ws + OFF_SRTQ);
    float* out = (float*)d_out;

    hipMemsetAsync(cnt, 0, 2 * N_LIC * sizeof(int), stream);

    prep_kernel<<<(256 * 576 + 256 + 255) / 256, 256, 0, stream>>>(Wl_p, Wl_q, Wr_p, Wr_q, b_p, b_q, Bpk, bias);

    convert_kernel<<<(N_LIC * 256 / 4) / 256, 256, 0, stream>>>(x_lic, xl);

    count_kernel<<<(E_P + E_Q + 255) / 256, 256, 0, stream>>>(ei_p_dst, ei_q_dst, cnt);

    scan_kernel<<<2, 1024, 0, stream>>>(cnt, offp, offq, curp, curq);

    fill_kernel<<<(E_P + E_Q + 255) / 256, 256, 0, stream>>>(ei_p_src, ei_p_dst, ei_q_src, ei_q_dst,
                                                             curp, curq, srtp, srtq);

    aggP_kernel<<<N_LIC / 8, 256, 0, stream>>>(x_emp, offp, srtp, aggp);
    aggQ_kernel<<<N_LIC / 16, 256, 0, stream>>>(x_con, offq, srtq, aggq);

    gemm_kernel<<<N_LIC / 64, 256, 0, stream>>>(aggp, aggq, xl, Bpk, bias, out);
}